// Round 28
// baseline (54.895 us; speedup 1.0000x reference)
//
#include <hip/hip_runtime.h>

#define KS    13
#define HALF  6
#define TY    64              // amplification/stream optimum (32->54.0, 64->51.9, 128->57.4)
#define NITER (TY + 12)       // 76 staged rows
#define NKH   38              // H iterations (2 rows each)
#define NKT   39              // total iterations: V lags H by one
#define IMG_H 1024
#define IMG_W 1024

typedef float vfloat4 __attribute__((ext_vector_type(4)));  // native vec for nt-store

__device__ __forceinline__ int reflect_idx(int i, int n) {
    if (i < 0) i = -i;
    if (i >= n) i = 2 * n - 2 - i;
    return i;
}

struct Ctx {
    const float* xin;
    float*       o;
    float        g[KS];
    int          t;        // threadIdx.x (0..511)
    int          r0;       // strip's first output row
    bool         interior; // H-half: 2 <= t <= 253 -> no column reflect
};

__device__ __forceinline__ void nt_store4(float* p, const float4& a) {
    vfloat4 v = { a.x, a.y, a.z, a.w };
    __builtin_nontemporal_store(v, reinterpret_cast<vfloat4*>(p));
}

// H-filter one staged row from LDS: 20-float window -> 4 outputs (H-half only).
__device__ __forceinline__ float4 h_filter(const float* srow, const Ctx& cx) {
    float f[20];
    if (cx.interior) {
        #pragma unroll
        for (int k = 0; k < 5; ++k) {
            float4 v = *reinterpret_cast<const float4*>(srow + 4 * cx.t - 8 + 4 * k);
            f[4*k+0] = v.x; f[4*k+1] = v.y; f[4*k+2] = v.z; f[4*k+3] = v.w;
        }
    } else {
        #pragma unroll
        for (int k = 0; k < 20; ++k)
            f[k] = srow[reflect_idx(4 * cx.t - 8 + k, IMG_W)];
    }
    float4 h = make_float4(0.f, 0.f, 0.f, 0.f);
    #pragma unroll
    for (int j = 0; j < KS; ++j) {
        h.x += cx.g[j] * f[2 + j];
        h.y += cx.g[j] * f[3 + j];
        h.z += cx.g[j] * f[4 + j];
        h.w += cx.g[j] * f[5 + j];
    }
    return h;
}

// Producer/consumer iteration k (= outer*7 + U, k uniform across block):
//  H-half (waves 0-3, t<256):
//    pre-barrier : ds_write raw pair (k&1) <- cur (rows 2k,2k+1); prefetch next
//    post-barrier: 10 ds_read raw, 2x h_filter, ds_write H-ring pair (k&1)
//  V-half (waves 4-7, t>=256), granule vt=t-256:
//    post-barrier: read H rows 2k-2,2k-1 from ring pair ((k-1)&1) into window
//                  slots (2U+12)%14,(2U+13)%14 [H wrote them in iter k-1,
//                  separated by barrier k]; then (k>=7) V-filter -> image rows
//                  r0+2k-14, r0+2k-13 (taps slots (2U+j)%14 / (2U+1+j)%14).
// Race audit (all cross-iter pairs separated by >=1 barrier):
//  raw[k&1]  : read post-bar k (H), rewritten pre-bar k+2 -- bar k+1 between.
//  ring[k&1] : written post-bar k (H), read post-bar k+1 (V), rewritten
//              post-bar k+2 (H) -- one barrier between each.
template<int U>
__device__ __forceinline__ void body2(int outer, const Ctx& cx,
                                      float (*sraw)[IMG_W], float (*sh)[IMG_W],
                                      float4 (&w)[14], float4& cur0, float4& cur1)
{
    const int k = outer * 7 + U;
    if (k >= NKT) return;                // block-uniform guard (barrier-safe)
    const bool isH = cx.t < 256;         // wave-aligned split (4H + 4V waves)
    const int bp = (k & 1) * 2;

    if (isH && k < NKH) {
        *reinterpret_cast<float4*>(&sraw[bp + 0][4 * cx.t]) = cur0;
        *reinterpret_cast<float4*>(&sraw[bp + 1][4 * cx.t]) = cur1;
        if (k + 1 < NKH) {               // prefetch rows 2k+2,2k+3 (T14)
            const int ra = reflect_idx(cx.r0 + 2 * k - 4, IMG_H);
            const int rb = reflect_idx(cx.r0 + 2 * k - 3, IMG_H);
            cur0 = *reinterpret_cast<const float4*>(cx.xin + (size_t)ra * IMG_W + 4 * cx.t);
            cur1 = *reinterpret_cast<const float4*>(cx.xin + (size_t)rb * IMG_W + 4 * cx.t);
        }
    }
    __syncthreads();

    if (isH) {
        if (k < NKH) {
            float4 h0 = h_filter(sraw[bp + 0], cx);
            float4 h1 = h_filter(sraw[bp + 1], cx);
            *reinterpret_cast<float4*>(&sh[bp + 0][4 * cx.t]) = h0;
            *reinterpret_cast<float4*>(&sh[bp + 1][4 * cx.t]) = h1;
        }
    } else {
        const int vt = cx.t - 256;
        const int rp = ((k - 1) & 1) * 2;    // ring pair written last iter
        if (k >= 1 && k <= NKH) {
            // load H rows 2k-2, 2k-1 into the rolling window
            w[(2 * U + 12) % 14] = *reinterpret_cast<const float4*>(&sh[rp + 0][4 * vt]);
            w[(2 * U + 13) % 14] = *reinterpret_cast<const float4*>(&sh[rp + 1][4 * vt]);
        }
        if (k >= 7) {
            float4 a0 = make_float4(0.f, 0.f, 0.f, 0.f);
            float4 a1 = make_float4(0.f, 0.f, 0.f, 0.f);
            #pragma unroll
            for (int j = 0; j < KS; ++j) {
                const float4 v0 = w[(2 * U + j) % 14];
                const float4 v1 = w[(2 * U + 1 + j) % 14];
                a0.x += cx.g[j] * v0.x;  a1.x += cx.g[j] * v1.x;
                a0.y += cx.g[j] * v0.y;  a1.y += cx.g[j] * v1.y;
                a0.z += cx.g[j] * v0.z;  a1.z += cx.g[j] * v1.z;
                a0.w += cx.g[j] * v0.w;  a1.w += cx.g[j] * v1.w;
            }
            nt_store4(cx.o + (size_t)(cx.r0 + 2 * k - 14) * IMG_W + 4 * vt, a0);
            nt_store4(cx.o + (size_t)(cx.r0 + 2 * k - 13) * IMG_W + 4 * vt, a1);
        }
    }
}

// 512 threads: waves 0-3 produce (stage+H), waves 4-7 consume (V+store).
// Per-wave critical path ~-35%; 2 blocks/CU x 8 waves = 16 waves/CU (50%).
// No launch-bounds min-waves (R2: VGPR cap -> spill). Expect ~105 VGPR.
__global__ __launch_bounds__(512) void gauss_blur_stream(
    const float* __restrict__ x, const float* __restrict__ k2d,
    float* __restrict__ out)
{
    __shared__ float sraw[4][IMG_W];   // raw row ping-pong pairs (16 KB)
    __shared__ float sh  [4][IMG_W];   // H-result ring pairs    (16 KB)

    Ctx cx;
    cx.t  = threadIdx.x;
    cx.r0 = blockIdx.x * TY;
    const int img = blockIdx.y;
    cx.xin = x + (size_t)img * IMG_H * IMG_W;
    cx.o   = out + (size_t)img * IMG_H * IMG_W;
    cx.interior = (cx.t >= 2) && (cx.t <= 253);

    // 1D taps: k2d = outer(g,g) exactly, g[i] = k2d[i][6]/sqrt(k2d[6][6])
    {
        float c   = k2d[HALF * KS + HALF];
        float inv = 1.0f / sqrtf(c);
        #pragma unroll
        for (int j = 0; j < KS; ++j) cx.g[j] = k2d[j * KS + HALF] * inv;
    }

    float4 w[14];
    float4 cur0 = make_float4(0.f, 0.f, 0.f, 0.f);
    float4 cur1 = cur0;
    if (cx.t < 256) {   // H-half preloads staged rows 0,1 (input r0-6, r0-5)
        cur0 = *reinterpret_cast<const float4*>(
            cx.xin + (size_t)reflect_idx(cx.r0 - 6, IMG_H) * IMG_W + 4 * cx.t);
        cur1 = *reinterpret_cast<const float4*>(
            cx.xin + (size_t)reflect_idx(cx.r0 - 5, IMG_H) * IMG_W + 4 * cx.t);
    }

    for (int outer = 0; outer < 6; ++outer) {   // 6*7 = 42 bodies, guard k<39
        body2<0>(outer, cx, sraw, sh, w, cur0, cur1);
        body2<1>(outer, cx, sraw, sh, w, cur0, cur1);
        body2<2>(outer, cx, sraw, sh, w, cur0, cur1);
        body2<3>(outer, cx, sraw, sh, w, cur0, cur1);
        body2<4>(outer, cx, sraw, sh, w, cur0, cur1);
        body2<5>(outer, cx, sraw, sh, w, cur0, cur1);
        body2<6>(outer, cx, sraw, sh, w, cur0, cur1);
    }
}

extern "C" void kernel_launch(void* const* d_in, const int* in_sizes, int n_in,
                              void* d_out, int out_size, void* d_ws, size_t ws_size,
                              hipStream_t stream) {
    const float* x   = (const float*)d_in[0];
    const float* k2d = (const float*)d_in[1];
    float*       out = (float*)d_out;

    dim3 grid(IMG_H / TY, 32);   // 16 strips x 32 images = 512 blocks (2/CU, 16 waves)
    gauss_blur_stream<<<grid, 512, 0, stream>>>(x, k2d, out);
}

// Round 29
// 51.284 us; speedup vs baseline: 1.0704x; 1.0704x over previous
//
#include <hip/hip_runtime.h>

#define KS    13
#define HALF  6
#define TY    64              // amplification/stream optimum (32->54.0, 64->51.9/51.3, 128->57.4)
#define NITER (TY + 12)       // 76 staged rows
#define NK    (NITER / 2)     // 38 iterations, 2 rows per barrier
#define IMG_H 1024
#define IMG_W 1024

typedef float vfloat4 __attribute__((ext_vector_type(4)));  // native vec for nt-store

__device__ __forceinline__ int reflect_idx(int i, int n) {
    if (i < 0) i = -i;
    if (i >= n) i = 2 * n - 2 - i;
    return i;
}

struct Ctx {
    const float* xin;
    float*       o;
    float        g[KS];
    int          t;        // thread's column granule: cols 4t..4t+3
    int          r0;       // strip's first output row
    bool         interior; // 2 <= t <= 253 : LDS window read needs no column reflect
};

// Nontemporal float4 store (output is write-once/never-read).
__device__ __forceinline__ void nt_store4(float* p, const float4& a) {
    vfloat4 v = { a.x, a.y, a.z, a.w };
    __builtin_nontemporal_store(v, reinterpret_cast<vfloat4*>(p));
}

// H-filter one staged row from LDS: 20-float window -> 4 outputs.
__device__ __forceinline__ float4 h_filter(const float* srow, const Ctx& cx) {
    float f[20];
    if (cx.interior) {
        #pragma unroll
        for (int k = 0; k < 5; ++k) {
            float4 v = *reinterpret_cast<const float4*>(srow + 4 * cx.t - 8 + 4 * k);
            f[4*k+0] = v.x; f[4*k+1] = v.y; f[4*k+2] = v.z; f[4*k+3] = v.w;
        }
    } else {
        #pragma unroll
        for (int k = 0; k < 20; ++k)
            f[k] = srow[reflect_idx(4 * cx.t - 8 + k, IMG_W)];
    }
    float4 h = make_float4(0.f, 0.f, 0.f, 0.f);
    #pragma unroll
    for (int j = 0; j < KS; ++j) {
        h.x += cx.g[j] * f[2 + j];
        h.y += cx.g[j] * f[3 + j];
        h.z += cx.g[j] * f[4 + j];
        h.w += cx.g[j] * f[5 + j];
    }
    return h;
}

// Iteration k (= outer*7 + U, U == k mod 7): stage rows 2k,2k+1 -> (k&1) LDS
// pair; prefetch rows 2k+2,2k+3 (T14); barrier; V[k-1] (lagged, pure register
// math overlapping H's ds_reads) -> output rows r0+2k-14, r0+2k-13; then H[k]
// into slots (2U)%14,(2U+1)%14 (row m lives at slot m%14; 2k%14 == 2U).
// Window indices compile-time (rule #20); ping-pong WAR proof as R13.
template<int U>
__device__ __forceinline__ void body2(int outer, const Ctx& cx, float (*s)[IMG_W],
                                      float4 (&w)[14], float4& cur0, float4& cur1)
{
    const int k = outer * 7 + U;
    if (k >= NK) return;                 // block-uniform guard (barrier-safe)
    const int n0 = 2 * k;
    const int bp = (k & 1) * 2;          // LDS buffer pair

    // commit staged rows; then issue next pair's loads (T14)
    *reinterpret_cast<float4*>(&s[bp + 0][4 * cx.t]) = cur0;
    *reinterpret_cast<float4*>(&s[bp + 1][4 * cx.t]) = cur1;
    if (k + 1 < NK) {
        const int ra = reflect_idx(cx.r0 + n0 - 4, IMG_H);  // row n0+2
        const int rb = reflect_idx(cx.r0 + n0 - 3, IMG_H);  // row n0+3
        cur0 = *reinterpret_cast<const float4*>(cx.xin + (size_t)ra * IMG_W + 4 * cx.t);
        cur1 = *reinterpret_cast<const float4*>(cx.xin + (size_t)rb * IMG_W + 4 * cx.t);
    }
    __syncthreads();

    // V[k-1] (lagged): output rows r0+n0-14, r0+n0-13; taps slots (2U+j)%14,
    // (2U+1+j)%14 -- all pre-H window values.
    if (n0 >= 14) {
        float4 a0 = make_float4(0.f, 0.f, 0.f, 0.f);
        float4 a1 = make_float4(0.f, 0.f, 0.f, 0.f);
        #pragma unroll
        for (int j = 0; j < KS; ++j) {
            const float4 v0 = w[(2 * U + j) % 14];
            const float4 v1 = w[(2 * U + 1 + j) % 14];
            a0.x += cx.g[j] * v0.x;  a1.x += cx.g[j] * v1.x;
            a0.y += cx.g[j] * v0.y;  a1.y += cx.g[j] * v1.y;
            a0.z += cx.g[j] * v0.z;  a1.z += cx.g[j] * v1.z;
            a0.w += cx.g[j] * v0.w;  a1.w += cx.g[j] * v1.w;
        }
        nt_store4(cx.o + (size_t)(cx.r0 + n0 - 14) * IMG_W + 4 * cx.t, a0);
        nt_store4(cx.o + (size_t)(cx.r0 + n0 - 13) * IMG_W + 4 * cx.t, a1);
    }

    // H[k]: ds_reads are independent of the V math above -> scheduler overlaps
    w[(2 * U) % 14]     = h_filter(s[bp + 0], cx);
    w[(2 * U + 1) % 14] = h_filter(s[bp + 1], cx);
}

// No launch-bounds min-waves (R2: VGPR cap -> spill). 96 VGPR measured.
__global__ __launch_bounds__(256) void gauss_blur_stream(
    const float* __restrict__ x, const float* __restrict__ k2d,
    float* __restrict__ out)
{
    __shared__ float s[4][IMG_W];   // 16384 B: two ping-pong row PAIRS

    Ctx cx;
    cx.t  = threadIdx.x;
    cx.r0 = blockIdx.x * TY;
    const int img = blockIdx.y;
    cx.xin = x + (size_t)img * IMG_H * IMG_W;
    cx.o   = out + (size_t)img * IMG_H * IMG_W;
    cx.interior = (cx.t >= 2) && (cx.t <= 253);

    // 1D taps: k2d = outer(g,g) exactly, g[i] = k2d[i][6]/sqrt(k2d[6][6])
    {
        float c   = k2d[HALF * KS + HALF];
        float inv = 1.0f / sqrtf(c);
        #pragma unroll
        for (int j = 0; j < KS; ++j) cx.g[j] = k2d[j * KS + HALF] * inv;
    }

    float4 w[14];
    // preload rows n=0,1 (input rows r0-6, r0-5, reflected)
    float4 cur0 = *reinterpret_cast<const float4*>(
        cx.xin + (size_t)reflect_idx(cx.r0 - 6, IMG_H) * IMG_W + 4 * cx.t);
    float4 cur1 = *reinterpret_cast<const float4*>(
        cx.xin + (size_t)reflect_idx(cx.r0 - 5, IMG_H) * IMG_W + 4 * cx.t);

    for (int outer = 0; outer < 6; ++outer) {   // 6*7 = 42 bodies, guard k<38
        body2<0>(outer, cx, s, w, cur0, cur1);
        body2<1>(outer, cx, s, w, cur0, cur1);
        body2<2>(outer, cx, s, w, cur0, cur1);
        body2<3>(outer, cx, s, w, cur0, cur1);
        body2<4>(outer, cx, s, w, cur0, cur1);
        body2<5>(outer, cx, s, w, cur0, cur1);
        body2<6>(outer, cx, s, w, cur0, cur1);
    }

    // epilogue: V[37] -> output rows r0+62, r0+63. As-if k'=38 (38 mod 7 = 3):
    // taps slots (6+j)%14, (7+j)%14.
    {
        float4 a0 = make_float4(0.f, 0.f, 0.f, 0.f);
        float4 a1 = make_float4(0.f, 0.f, 0.f, 0.f);
        #pragma unroll
        for (int j = 0; j < KS; ++j) {
            const float4 v0 = w[(6 + j) % 14];
            const float4 v1 = w[(7 + j) % 14];
            a0.x += cx.g[j] * v0.x;  a1.x += cx.g[j] * v1.x;
            a0.y += cx.g[j] * v0.y;  a1.y += cx.g[j] * v1.y;
            a0.z += cx.g[j] * v0.z;  a1.z += cx.g[j] * v1.z;
            a0.w += cx.g[j] * v0.w;  a1.w += cx.g[j] * v1.w;
        }
        nt_store4(cx.o + (size_t)(cx.r0 + 62) * IMG_W + 4 * cx.t, a0);
        nt_store4(cx.o + (size_t)(cx.r0 + 63) * IMG_W + 4 * cx.t, a1);
    }
}

extern "C" void kernel_launch(void* const* d_in, const int* in_sizes, int n_in,
                              void* d_out, int out_size, void* d_ws, size_t ws_size,
                              hipStream_t stream) {
    const float* x   = (const float*)d_in[0];
    const float* k2d = (const float*)d_in[1];
    float*       out = (float*)d_out;

    dim3 grid(IMG_H / TY, 32);   // 16 strips x 32 images = 512 blocks
    gauss_blur_stream<<<grid, 256, 0, stream>>>(x, k2d, out);
}